// Round 9
// baseline (1415.221 us; speedup 1.0000x reference)
//
#include <hip/hip_runtime.h>
#include <hip/hip_bf16.h>
#include <math.h>

#define Nn  50000
#define NR  50048   // rows padded to 64
#define En  800000
#define DIN 500
#define Hd  128
#define Cc  40
#define Bb  10000
#define Ll  9
#define KT  5

typedef short bf16x8 __attribute__((ext_vector_type(8)));
typedef unsigned short u16x8 __attribute__((ext_vector_type(8)));
typedef float f32x4 __attribute__((ext_vector_type(4)));

__device__ inline float bf2f(unsigned short u) {
  union { unsigned int i; float f; } c; c.i = (unsigned int)u << 16; return c.f;
}
__device__ inline unsigned short f2bf(float f) {
  __hip_bfloat16 b = __float2bfloat16(f);
  return *(unsigned short*)&b;
}

// ---------------- weight packing into B-fragment layout ----------------
__global__ __launch_bounds__(256) void k_pack_w1(const float* __restrict__ W1,
                                                 unsigned short* __restrict__ W1p) {
  const int id = blockIdx.x * 256 + threadIdx.x;   // 16*4*128*8 = 65536
  if (id >= 65536) return;
  const int j = id & 7, col = (id >> 3) & 127, qk = id >> 10;  // qk = kk*4+quad
  const int k = (qk >> 2) * 32 + (qk & 3) * 8 + j;
  W1p[id] = f2bf((k < DIN) ? W1[(size_t)k * Hd + col] : 0.f);
}

// Wcat[l] = [W1l ; 0.5*W2l]  (K=256), same frag packing, 32768 elems/layer
__global__ __launch_bounds__(256) void k_pack_wc(const float* __restrict__ cw1,
    const float* __restrict__ cw2, unsigned short* __restrict__ Wcp) {
  const int id = blockIdx.x * 256 + threadIdx.x;   // 9*32768 = 294912
  if (id >= 294912) return;
  const int j = id & 7, col = (id >> 3) & 127, qk = (id >> 10) & 31, l = id >> 15;
  const int k = (qk >> 2) * 32 + (qk & 3) * 8 + j;  // 0..255
  float v;
  if (k < 128) v = cw1[((size_t)l * 128 + k) * 128 + col];
  else         v = 0.5f * cw2[((size_t)l * 128 + (k - 128)) * 128 + col];
  Wcp[id] = f2bf(v);
}

// ---------------- input GEMM (MFMA): h = relu(x @ W1 + b1) ----------------
__global__ __launch_bounds__(256) void k_in(const float* __restrict__ x,
    const unsigned short* __restrict__ W1p, const float* __restrict__ b1,
    float* __restrict__ h, unsigned short* __restrict__ hb,
    unsigned short* __restrict__ x0b) {
  const int tid = threadIdx.x;
  const int wv = tid >> 6, lane = tid & 63;
  const int lrow = lane & 15, quad = lane >> 4;
  const int row0 = blockIdx.x * 64;
  const int ar = row0 + wv * 16 + lrow;
  f32x4 acc[8];
#pragma unroll
  for (int t = 0; t < 8; ++t) acc[t] = (f32x4){0.f, 0.f, 0.f, 0.f};

  for (int kk = 0; kk < 16; ++kk) {
    const int kbase = kk * 32 + quad * 8;
    float av[8];
    if (ar < Nn) {
      if (kk < 15) {
        const float4 p0 = *(const float4*)(x + (size_t)ar * DIN + kbase);
        const float4 p1 = *(const float4*)(x + (size_t)ar * DIN + kbase + 4);
        av[0] = p0.x; av[1] = p0.y; av[2] = p0.z; av[3] = p0.w;
        av[4] = p1.x; av[5] = p1.y; av[6] = p1.z; av[7] = p1.w;
      } else {
#pragma unroll
        for (int j = 0; j < 8; ++j)
          av[j] = (kbase + j < DIN) ? x[(size_t)ar * DIN + kbase + j] : 0.f;
      }
    } else {
#pragma unroll
      for (int j = 0; j < 8; ++j) av[j] = 0.f;
    }
    bf16x8 af;
#pragma unroll
    for (int j = 0; j < 8; ++j) af[j] = (short)f2bf(av[j]);
#pragma unroll
    for (int nt = 0; nt < 8; ++nt) {
      const bf16x8 bf = *(const bf16x8*)(W1p + ((size_t)(kk * 4 + quad) * 128 + nt * 16 + lrow) * 8);
      acc[nt] = __builtin_amdgcn_mfma_f32_16x16x32_bf16(af, bf, acc[nt], 0, 0, 0);
    }
  }

  __shared__ float sacc[64 * 132];
#pragma unroll
  for (int nt = 0; nt < 8; ++nt)
#pragma unroll
    for (int i = 0; i < 4; ++i)
      sacc[(wv * 16 + quad * 4 + i) * 132 + nt * 16 + lrow] = acc[nt][i];
  __syncthreads();

  const int row = tid >> 2, cs = (tid & 3) * 32;
  const int gr = row0 + row;
  if (gr < Nn) {
#pragma unroll
    for (int g = 0; g < 4; ++g) {
      const int c0 = cs + g * 8;
      float v[8];
#pragma unroll
      for (int j = 0; j < 8; ++j)
        v[j] = fmaxf(sacc[row * 132 + c0 + j] + b1[c0 + j], 0.f);
      float4 o0 = {v[0], v[1], v[2], v[3]}, o1 = {v[4], v[5], v[6], v[7]};
      *(float4*)(h + (size_t)gr * Hd + c0) = o0;
      *(float4*)(h + (size_t)gr * Hd + c0 + 4) = o1;
      u16x8 ob;
#pragma unroll
      for (int j = 0; j < 8; ++j) ob[j] = f2bf(v[j]);
      *(u16x8*)(hb + (size_t)gr * Hd + c0) = ob;
      *(u16x8*)(x0b + (size_t)gr * Hd + c0) = ob;
    }
  }
}

// ---------------- CSR build ----------------
__global__ void k_hist(const int* __restrict__ rows, int* __restrict__ counts) {
  int e = blockIdx.x * 256 + threadIdx.x;
  if (e < En) atomicAdd(&counts[rows[e]], 1);
}

__global__ __launch_bounds__(1024) void k_scan(const int* __restrict__ counts,
                                               int* __restrict__ ptr) {
  __shared__ int buf[1024];
  __shared__ int s_base;
  const int tid = threadIdx.x;
  if (tid == 0) { s_base = 0; ptr[0] = 0; }
  __syncthreads();
  for (int start = 0; start < Nn; start += 1024) {
    int i = start + tid;
    int v = (i < Nn) ? counts[i] : 0;
    buf[tid] = v;
    __syncthreads();
    for (int off = 1; off < 1024; off <<= 1) {
      int t = (tid >= off) ? buf[tid - off] : 0;
      __syncthreads();
      buf[tid] += t;
      __syncthreads();
    }
    if (i < Nn) ptr[i + 1] = s_base + buf[tid];
    __syncthreads();
    if (tid == 0) s_base += buf[1023];
    __syncthreads();
  }
}

__global__ void k_scatter(const int* __restrict__ rows, const int* __restrict__ cols,
                          const float* __restrict__ w, const int* __restrict__ ptr,
                          int* __restrict__ fill, int* __restrict__ csr_col,
                          float* __restrict__ csr_w) {
  int e = blockIdx.x * 256 + threadIdx.x;
  if (e >= En) return;
  int r = rows[e];
  int pos = atomicAdd(&fill[r], 1);
  int d = ptr[r] + pos;
  csr_col[d] = cols[e];
  csr_w[d] = w[e];
}

// ---------------- fused spmm + layer ------------------------------------------
// Phase 1: per 64-row block, gather p = 0.5*segsum(w*hbin[col]) into LDS (bf16,
//   same rounding point as the old global pb -> identical numerics).
// Phase 2: MFMA [p;x0] @ Wcat + epilogue, p A-frags/epilogue read from LDS.
// hb is double-buffered across layers (blocks gather rows other blocks own).
#define SP_LD 136
__global__ __launch_bounds__(256) void k_splayer(const int* __restrict__ ptr,
    const int* __restrict__ csr_col, const float* __restrict__ csr_w,
    const unsigned short* __restrict__ hbin, const unsigned short* __restrict__ x0b,
    const unsigned short* __restrict__ Wcp, float* __restrict__ h,
    unsigned short* __restrict__ hbout, float beta) {
  __shared__ __align__(16) unsigned short sp[64 * SP_LD];
  __shared__ float sacc[64 * 132];
  const int tid = threadIdx.x;
  const int wv = tid >> 6, lane = tid & 63;
  const int g = lane >> 4;        // edge group 0..3
  const int fl = lane & 15;       // feature lane: feats fl*8 .. fl*8+7
  const int row0 = blockIdx.x * 64;

  // ---- phase 1: gather (proven group-strided x4 spmm inner loop) ----
  for (int rr = 0; rr < 16; ++rr) {
    const int row = row0 + wv * 16 + rr;
    float acc[8];
#pragma unroll
    for (int j = 0; j < 8; ++j) acc[j] = 0.f;
    if (row < Nn) {
      const int s = ptr[row], e_end = ptr[row + 1];
      auto acc8 = [&](uint4 v, float w) {
        union { unsigned int i; float f; } t;
        t.i = v.x << 16;         acc[0] += w * t.f;
        t.i = v.x & 0xFFFF0000u; acc[1] += w * t.f;
        t.i = v.y << 16;         acc[2] += w * t.f;
        t.i = v.y & 0xFFFF0000u; acc[3] += w * t.f;
        t.i = v.z << 16;         acc[4] += w * t.f;
        t.i = v.z & 0xFFFF0000u; acc[5] += w * t.f;
        t.i = v.w << 16;         acc[6] += w * t.f;
        t.i = v.w & 0xFFFF0000u; acc[7] += w * t.f;
      };
      int e = s + g;
      for (; e + 12 < e_end; e += 16) {
        const int c0 = csr_col[e];
        const int c1 = csr_col[e + 4];
        const int c2 = csr_col[e + 8];
        const int c3 = csr_col[e + 12];
        const float w0 = csr_w[e];
        const float w1 = csr_w[e + 4];
        const float w2 = csr_w[e + 8];
        const float w3 = csr_w[e + 12];
        const uint4 v0 = *(const uint4*)(hbin + (size_t)c0 * Hd + fl * 8);
        const uint4 v1 = *(const uint4*)(hbin + (size_t)c1 * Hd + fl * 8);
        const uint4 v2 = *(const uint4*)(hbin + (size_t)c2 * Hd + fl * 8);
        const uint4 v3 = *(const uint4*)(hbin + (size_t)c3 * Hd + fl * 8);
        acc8(v0, w0); acc8(v1, w1); acc8(v2, w2); acc8(v3, w3);
      }
      for (; e + 4 < e_end; e += 8) {
        const int c0 = csr_col[e];
        const int c1 = csr_col[e + 4];
        const float w0 = csr_w[e];
        const float w1 = csr_w[e + 4];
        const uint4 v0 = *(const uint4*)(hbin + (size_t)c0 * Hd + fl * 8);
        const uint4 v1 = *(const uint4*)(hbin + (size_t)c1 * Hd + fl * 8);
        acc8(v0, w0); acc8(v1, w1);
      }
      if (e < e_end) {
        const int c = csr_col[e];
        const float w = csr_w[e];
        const uint4 v = *(const uint4*)(hbin + (size_t)c * Hd + fl * 8);
        acc8(v, w);
      }
    }
#pragma unroll
    for (int j = 0; j < 8; ++j) acc[j] += __shfl_xor(acc[j], 16);
#pragma unroll
    for (int j = 0; j < 8; ++j) acc[j] += __shfl_xor(acc[j], 32);
    if (g == 0) {
      uint4 o;
      o.x = (unsigned int)f2bf(0.5f * acc[0]) | ((unsigned int)f2bf(0.5f * acc[1]) << 16);
      o.y = (unsigned int)f2bf(0.5f * acc[2]) | ((unsigned int)f2bf(0.5f * acc[3]) << 16);
      o.z = (unsigned int)f2bf(0.5f * acc[4]) | ((unsigned int)f2bf(0.5f * acc[5]) << 16);
      o.w = (unsigned int)f2bf(0.5f * acc[6]) | ((unsigned int)f2bf(0.5f * acc[7]) << 16);
      *(uint4*)&sp[(wv * 16 + rr) * SP_LD + fl * 8] = o;
    }
  }
  __syncthreads();

  // ---- phase 2: MFMA (p from LDS, x0 from global) ----
  const int lrow = lane & 15, quad = lane >> 4;
  const int ar = row0 + wv * 16 + lrow;
  const int lr = wv * 16 + lrow;
  f32x4 macc[8];
#pragma unroll
  for (int t = 0; t < 8; ++t) macc[t] = (f32x4){0.f, 0.f, 0.f, 0.f};

#pragma unroll
  for (int kk = 0; kk < 8; ++kk) {
    const int ko = (kk & 3) * 32 + quad * 8;
    bf16x8 af;
    if (kk < 4) af = *(const bf16x8*)&sp[lr * SP_LD + ko];
    else        af = *(const bf16x8*)(x0b + (size_t)ar * Hd + ko);
#pragma unroll
    for (int nt = 0; nt < 8; ++nt) {
      const bf16x8 bf = *(const bf16x8*)(Wcp + ((size_t)(kk * 4 + quad) * 128 + nt * 16 + lrow) * 8);
      macc[nt] = __builtin_amdgcn_mfma_f32_16x16x32_bf16(af, bf, macc[nt], 0, 0, 0);
    }
  }

#pragma unroll
  for (int nt = 0; nt < 8; ++nt)
#pragma unroll
    for (int i = 0; i < 4; ++i)
      sacc[(wv * 16 + quad * 4 + i) * 132 + nt * 16 + lrow] = macc[nt][i];
  __syncthreads();

  const int row = tid >> 2, cs = (tid & 3) * 32;
  const int gr = row0 + row;
  if (gr < Nn) {
    const float om = 1.f - beta;
#pragma unroll
    for (int g2 = 0; g2 < 4; ++g2) {
      const int c0 = cs + g2 * 8;
      const u16x8 pv = *(const u16x8*)&sp[row * SP_LD + c0];
      const u16x8 xv = *(const u16x8*)(x0b + (size_t)gr * Hd + c0);
      const float4 h0 = *(const float4*)(h + (size_t)gr * Hd + c0);
      const float4 h1 = *(const float4*)(h + (size_t)gr * Hd + c0 + 4);
      float hv[8] = {h0.x, h0.y, h0.z, h0.w, h1.x, h1.y, h1.z, h1.w};
      float nv[8];
#pragma unroll
      for (int j = 0; j < 8; ++j) {
        const float gemm = sacc[row * 132 + c0 + j];
        const float pj = bf2f(pv[j]);
        const float xj = bf2f(xv[j]);
        const float outv = om * (pj + 0.5f * xj) + beta * gemm;
        nv[j] = fmaxf(hv[j] + outv, 0.f);
      }
      float4 o0 = {nv[0], nv[1], nv[2], nv[3]}, o1 = {nv[4], nv[5], nv[6], nv[7]};
      *(float4*)(h + (size_t)gr * Hd + c0) = o0;
      *(float4*)(h + (size_t)gr * Hd + c0 + 4) = o1;
      u16x8 ob;
#pragma unroll
      for (int j = 0; j < 8; ++j) ob[j] = f2bf(nv[j]);
      *(u16x8*)(hbout + (size_t)gr * Hd + c0) = ob;
    }
  }
}

// ---------------- head ----------------
__global__ __launch_bounds__(256) void k_head(const float* __restrict__ h,
    const float* __restrict__ W2, const float* __restrict__ b2,
    unsigned short* __restrict__ anb, float* __restrict__ p_lc,
    float* __restrict__ out_emb) {
  const int wid = (blockIdx.x * 256 + threadIdx.x) >> 6;
  const int lane = threadIdx.x & 63;
  if (wid >= Bb) return;
  const float* hr = h + (size_t)wid * Hd;
  const float v0 = hr[lane], v1 = hr[lane + 64];
  out_emb[wid * Hd + lane] = v0;
  out_emb[wid * Hd + lane + 64] = v1;
  float ss = v0 * v0 + v1 * v1;
#pragma unroll
  for (int off = 32; off > 0; off >>= 1) ss += __shfl_xor(ss, off);
  const float inv = 1.f / fmaxf(sqrtf(ss), 1e-8f);
  anb[wid * Hd + lane] = f2bf(v0 * inv);
  anb[wid * Hd + lane + 64] = f2bf(v1 * inv);
  float l = 0.f;
  if (lane < Cc) {
    for (int k = 0; k < Hd; ++k) l += hr[k] * W2[k * Cc + lane];
    l += b2[lane];
  }
  float lm = (lane < Cc) ? l : -3.0e38f;
#pragma unroll
  for (int off = 32; off > 0; off >>= 1) lm = fmaxf(lm, __shfl_xor(lm, off));
  float ex = (lane < Cc) ? expf(l - lm) : 0.f;
#pragma unroll
  for (int off = 32; off > 0; off >>= 1) ex += __shfl_xor(ex, off);
  const float lse = logf(ex);
  if (lane < Cc) p_lc[wid * Cc + lane] = l - lm - lse;
}

// ---------------- fused sim = an@an^T (bf16 MFMA) with running top-5 ----------
// Round-2 measured-best structure: 256 thr, CH_N=4, guarded everywhere.
// (Guard-free full tiles NaN'd in r5/r6 — do not retry.)
#define CH_N  4
#define CH_SZ 2500
#define SB_LD 136
__global__ __launch_bounds__(256) void k_simtopk(const unsigned short* __restrict__ anb,
    float* __restrict__ cval, int* __restrict__ cidx) {
  __shared__ __align__(16) char smem[40960];
  unsigned short* sb = (unsigned short*)smem;
  const int rt = blockIdx.x / CH_N;
  const int chunk = blockIdx.x % CH_N;
  const int row0 = rt * 64;
  const int cbeg = chunk * CH_SZ;
  const int cend = cbeg + CH_SZ;
  const int tid = threadIdx.x;
  const int wv = tid >> 6;
  const int lane = tid & 63;
  const int lrow = lane & 15;
  const int quad = lane >> 4;

  union Frag { uint4 u4; bf16x8 v; };
  bf16x8 afr[4];
  const int ar = row0 + wv * 16 + lrow;
#pragma unroll
  for (int kq = 0; kq < 4; ++kq) {
    Frag f;
    f.u4 = make_uint4(0u, 0u, 0u, 0u);
    if (ar < Bb) f.u4 = *(const uint4*)(anb + (size_t)ar * Hd + kq * 32 + quad * 8);
    afr[kq] = f.v;
  }

  float bv[4][KT];
  int bi[4][KT];
#pragma unroll
  for (int r = 0; r < 4; ++r)
#pragma unroll
    for (int t = 0; t < KT; ++t) { bv[r][t] = -3.0e38f; bi[r][t] = 0x7fffffff; }

  const int ntile = (CH_SZ + 63) / 64;
  for (int t = 0; t < ntile; ++t) {
    const int c0 = cbeg + t * 64;
    __syncthreads();
    for (int i = tid; i < 1024; i += 256) {
      const int r = i >> 4, ch = i & 15;
      const int gc = c0 + r;
      uint4 v = make_uint4(0u, 0u, 0u, 0u);
      if (gc < cend) v = *(const uint4*)(anb + (size_t)gc * Hd + ch * 8);
      *(uint4*)&sb[r * SB_LD + ch * 8] = v;
    }
    __syncthreads();
#pragma unroll
    for (int sub = 0; sub < 4; ++sub) {
      f32x4 acc = {0.f, 0.f, 0.f, 0.f};
      const int scol = sub * 16 + lrow;
#pragma unroll
      for (int kq = 0; kq < 4; ++kq) {
        bf16x8 bfr = *(const bf16x8*)&sb[scol * SB_LD + kq * 32 + quad * 8];
        acc = __builtin_amdgcn_mfma_f32_16x16x32_bf16(afr[kq], bfr, acc, 0, 0, 0);
      }
      const int gc = c0 + scol;
      const bool ok = gc < cend;
#pragma unroll
      for (int i = 0; i < 4; ++i) {
        const float v = ok ? acc[i] : -3.0e38f;
        if (v > bv[i][KT - 1]) {
          float tv = v; int ti = gc;
#pragma unroll
          for (int s = 0; s < KT; ++s) {
            if (tv > bv[i][s]) {
              float ov = bv[i][s]; int oi = bi[i][s];
              bv[i][s] = tv; bi[i][s] = ti; tv = ov; ti = oi;
            }
          }
        }
      }
    }
  }

  __syncthreads();
  float* mv = (float*)smem;
  int* mi = (int*)(smem + 20480);
#pragma unroll
  for (int i = 0; i < 4; ++i) {
    const int row = wv * 16 + quad * 4 + i;
#pragma unroll
    for (int t = 0; t < KT; ++t) {
      mv[row * 80 + lrow * KT + t] = bv[i][t];
      mi[row * 80 + lrow * KT + t] = bi[i][t];
    }
  }
  __syncthreads();
  if (tid < 64) {
    const int gr = row0 + tid;
    if (gr < Bb) {
      float tv5[KT]; int ti5[KT];
#pragma unroll
      for (int t = 0; t < KT; ++t) { tv5[t] = -3.0e38f; ti5[t] = 0x7fffffff; }
      for (int m = 0; m < 80; ++m) {
        float v = mv[tid * 80 + m]; int id = mi[tid * 80 + m];
        if (v > tv5[KT - 1] || (v == tv5[KT - 1] && id < ti5[KT - 1])) {
#pragma unroll
          for (int s = 0; s < KT; ++s) {
            if (v > tv5[s] || (v == tv5[s] && id < ti5[s])) {
              float ov = tv5[s]; int oi = ti5[s];
              tv5[s] = v; ti5[s] = id; v = ov; id = oi;
            }
          }
        }
      }
#pragma unroll
      for (int t = 0; t < KT; ++t) {
        cval[gr * (CH_N * KT) + chunk * KT + t] = tv5[t];
        cidx[gr * (CH_N * KT) + chunk * KT + t] = ti5[t];
      }
    }
  }
}

// ---------------- final ----------------
__global__ __launch_bounds__(256) void k_final(const float* __restrict__ cval,
    const int* __restrict__ cidx, const int* __restrict__ y,
    const float* __restrict__ p_lc, float* __restrict__ out_final) {
  const int b = blockIdx.x * 256 + threadIdx.x;
  if (b >= Bb) return;
  float tv5[KT]; int ti5[KT];
#pragma unroll
  for (int t = 0; t < KT; ++t) { tv5[t] = -3.0e38f; ti5[t] = 0x7fffffff; }
#pragma unroll
  for (int m = 0; m < CH_N * KT; ++m) {
    float v = cval[b * (CH_N * KT) + m]; int id = cidx[b * (CH_N * KT) + m];
    if (v > tv5[KT - 1] || (v == tv5[KT - 1] && id < ti5[KT - 1])) {
#pragma unroll
      for (int t = 0; t < KT; ++t) {
        if (v > tv5[t] || (v == tv5[t] && id < ti5[t])) {
          float ov = tv5[t]; int oi = ti5[t];
          tv5[t] = v; ti5[t] = id; v = ov; id = oi;
        }
      }
    }
  }
  float w[KT]; int cls[KT];
#pragma unroll
  for (int t = 0; t < KT; ++t) { w[t] = expf(tv5[t]); cls[t] = y[ti5[t]]; }
  float m = -3.0e38f;
  for (int c = 0; c < Cc; ++c) {
    float f = 0.f;
#pragma unroll
    for (int t = 0; t < KT; ++t) f += (cls[t] == c) ? w[t] : 0.f;
    m = fmaxf(m, f);
  }
  float s = 0.f;
  for (int c = 0; c < Cc; ++c) {
    float f = 0.f;
#pragma unroll
    for (int t = 0; t < KT; ++t) f += (cls[t] == c) ? w[t] : 0.f;
    s += expf(f - m);
  }
  const float lse = logf(s);
  for (int c = 0; c < Cc; ++c) {
    float f = 0.f;
#pragma unroll
    for (int t = 0; t < KT; ++t) f += (cls[t] == c) ? w[t] : 0.f;
    out_final[b * Cc + c] = 0.5f * p_lc[b * Cc + c] + 0.5f * (f - m - lse);
  }
}

extern "C" void kernel_launch(void* const* d_in, const int* in_sizes, int n_in,
                              void* d_out, int out_size, void* d_ws, size_t ws_size,
                              hipStream_t stream) {
  const float* x  = (const float*)d_in[0];
  const int* erow = (const int*)d_in[1];
  const int* ecol = erow + En;
  const float* ew = (const float*)d_in[2];
  const int* y    = (const int*)d_in[3];
  const float* W1 = (const float*)d_in[5];
  const float* b1 = (const float*)d_in[6];
  const float* cw1 = (const float*)d_in[7];
  const float* cw2 = (const float*)d_in[8];
  const float* W2 = (const float*)d_in[9];
  const float* b2 = (const float*)d_in[10];
  float* out = (float*)d_out;

  float* ws = (float*)d_ws;
  size_t off = 0;
  float* h   = ws + off; off += (size_t)NR * Hd;
  float* plc = ws + off; off += (size_t)Bb * Cc;
  float* cval = ws + off; off += (size_t)Bb * (CH_N * KT);
  int* cidx  = (int*)(ws + off); off += (size_t)Bb * (CH_N * KT);
  int* counts = (int*)(ws + off); off += Nn;
  int* fill   = (int*)(ws + off); off += Nn;
  int* rptr   = (int*)(ws + off); off += Nn + 4;
  int* ccol   = (int*)(ws + off); off += En;
  float* cwt  = ws + off; off += En;
  unsigned short* anb = (unsigned short*)(ws + off); off += (size_t)Bb * Hd / 2;
  unsigned short* hba = (unsigned short*)(ws + off); off += (size_t)NR * Hd / 2;
  unsigned short* x0b = (unsigned short*)(ws + off); off += (size_t)NR * Hd / 2;
  unsigned short* hbb = (unsigned short*)(ws + off); off += (size_t)NR * Hd / 2;
  unsigned short* W1p = (unsigned short*)(ws + off); off += 65536 / 2;
  unsigned short* Wcp = (unsigned short*)(ws + off); off += 294912 / 2;

  k_pack_w1<<<256, 256, 0, stream>>>(W1, W1p);
  k_pack_wc<<<1152, 256, 0, stream>>>(cw1, cw2, Wcp);
  k_in<<<NR / 64, 256, 0, stream>>>(x, W1p, b1, h, hba, x0b);
  hipMemsetAsync(counts, 0, (size_t)2 * Nn * sizeof(int), stream);
  k_hist<<<(En + 255) / 256, 256, 0, stream>>>(erow, counts);
  k_scan<<<1, 1024, 0, stream>>>(counts, rptr);
  k_scatter<<<(En + 255) / 256, 256, 0, stream>>>(erow, ecol, ew, rptr, fill, ccol, cwt);
  for (int l = 0; l < Ll; ++l) {
    const float beta = logf(1.0f / (float)(l + 1) + 1.0f);
    const unsigned short* hin = (l & 1) ? hbb : hba;
    unsigned short* hout = (l & 1) ? hba : hbb;
    k_splayer<<<NR / 64, 256, 0, stream>>>(rptr, ccol, cwt, hin, x0b,
                                           Wcp + (size_t)l * 32768, h, hout, beta);
  }
  k_head<<<(Bb * 64) / 256, 256, 0, stream>>>(h, W2, b2, anb, plc, out + (size_t)Bb * Cc);
  k_simtopk<<<((Bb + 63) / 64) * CH_N, 256, 0, stream>>>(anb, cval, cidx);
  k_final<<<(Bb + 255) / 256, 256, 0, stream>>>(cval, cidx, y, plc, out);
}

// Round 10
// 1066.331 us; speedup vs baseline: 1.3272x; 1.3272x over previous
//
#include <hip/hip_runtime.h>
#include <hip/hip_bf16.h>
#include <math.h>

#define Nn  50000
#define NR  50048   // rows padded to 64
#define En  800000
#define DIN 500
#define Hd  128
#define Cc  40
#define Bb  10000
#define Ll  9
#define KT  5

typedef short bf16x8 __attribute__((ext_vector_type(8)));
typedef unsigned short u16x8 __attribute__((ext_vector_type(8)));
typedef float f32x4 __attribute__((ext_vector_type(4)));

__device__ inline float bf2f(unsigned short u) {
  union { unsigned int i; float f; } c; c.i = (unsigned int)u << 16; return c.f;
}
__device__ inline unsigned short f2bf(float f) {
  __hip_bfloat16 b = __float2bfloat16(f);
  return *(unsigned short*)&b;
}

// ---------------- weight packing into B-fragment layout ----------------
__global__ __launch_bounds__(256) void k_pack_w1(const float* __restrict__ W1,
                                                 unsigned short* __restrict__ W1p) {
  const int id = blockIdx.x * 256 + threadIdx.x;   // 16*4*128*8 = 65536
  if (id >= 65536) return;
  const int j = id & 7, col = (id >> 3) & 127, qk = id >> 10;  // qk = kk*4+quad
  const int k = (qk >> 2) * 32 + (qk & 3) * 8 + j;
  W1p[id] = f2bf((k < DIN) ? W1[(size_t)k * Hd + col] : 0.f);
}

// Wcat[l] = [W1l ; 0.5*W2l]  (K=256), same frag packing, 32768 elems/layer
__global__ __launch_bounds__(256) void k_pack_wc(const float* __restrict__ cw1,
    const float* __restrict__ cw2, unsigned short* __restrict__ Wcp) {
  const int id = blockIdx.x * 256 + threadIdx.x;   // 9*32768 = 294912
  if (id >= 294912) return;
  const int j = id & 7, col = (id >> 3) & 127, qk = (id >> 10) & 31, l = id >> 15;
  const int k = (qk >> 2) * 32 + (qk & 3) * 8 + j;  // 0..255
  float v;
  if (k < 128) v = cw1[((size_t)l * 128 + k) * 128 + col];
  else         v = 0.5f * cw2[((size_t)l * 128 + (k - 128)) * 128 + col];
  Wcp[id] = f2bf(v);
}

// ---------------- input GEMM (MFMA): hb = bf16(relu(x @ W1 + b1)) ----------------
__global__ __launch_bounds__(256) void k_in(const float* __restrict__ x,
    const unsigned short* __restrict__ W1p, const float* __restrict__ b1,
    unsigned short* __restrict__ hb, unsigned short* __restrict__ x0b) {
  const int tid = threadIdx.x;
  const int wv = tid >> 6, lane = tid & 63;
  const int lrow = lane & 15, quad = lane >> 4;
  const int row0 = blockIdx.x * 64;
  const int ar = row0 + wv * 16 + lrow;
  f32x4 acc[8];
#pragma unroll
  for (int t = 0; t < 8; ++t) acc[t] = (f32x4){0.f, 0.f, 0.f, 0.f};

  for (int kk = 0; kk < 16; ++kk) {
    const int kbase = kk * 32 + quad * 8;
    float av[8];
    if (ar < Nn) {
      if (kk < 15) {
        const float4 p0 = *(const float4*)(x + (size_t)ar * DIN + kbase);
        const float4 p1 = *(const float4*)(x + (size_t)ar * DIN + kbase + 4);
        av[0] = p0.x; av[1] = p0.y; av[2] = p0.z; av[3] = p0.w;
        av[4] = p1.x; av[5] = p1.y; av[6] = p1.z; av[7] = p1.w;
      } else {
#pragma unroll
        for (int j = 0; j < 8; ++j)
          av[j] = (kbase + j < DIN) ? x[(size_t)ar * DIN + kbase + j] : 0.f;
      }
    } else {
#pragma unroll
      for (int j = 0; j < 8; ++j) av[j] = 0.f;
    }
    bf16x8 af;
#pragma unroll
    for (int j = 0; j < 8; ++j) af[j] = (short)f2bf(av[j]);
#pragma unroll
    for (int nt = 0; nt < 8; ++nt) {
      const bf16x8 bf = *(const bf16x8*)(W1p + ((size_t)(kk * 4 + quad) * 128 + nt * 16 + lrow) * 8);
      acc[nt] = __builtin_amdgcn_mfma_f32_16x16x32_bf16(af, bf, acc[nt], 0, 0, 0);
    }
  }

  __shared__ float sacc[64 * 132];
#pragma unroll
  for (int nt = 0; nt < 8; ++nt)
#pragma unroll
    for (int i = 0; i < 4; ++i)
      sacc[(wv * 16 + quad * 4 + i) * 132 + nt * 16 + lrow] = acc[nt][i];
  __syncthreads();

  const int row = tid >> 2, cs = (tid & 3) * 32;
  const int gr = row0 + row;
  if (gr < Nn) {
#pragma unroll
    for (int g = 0; g < 4; ++g) {
      const int c0 = cs + g * 8;
      float v[8];
#pragma unroll
      for (int j = 0; j < 8; ++j)
        v[j] = fmaxf(sacc[row * 132 + c0 + j] + b1[c0 + j], 0.f);
      u16x8 ob;
#pragma unroll
      for (int j = 0; j < 8; ++j) ob[j] = f2bf(v[j]);
      *(u16x8*)(hb + (size_t)gr * Hd + c0) = ob;
      *(u16x8*)(x0b + (size_t)gr * Hd + c0) = ob;
    }
  }
}

// ---------------- CSR build ----------------
__global__ void k_hist(const int* __restrict__ rows, int* __restrict__ counts) {
  int e = blockIdx.x * 256 + threadIdx.x;
  if (e < En) atomicAdd(&counts[rows[e]], 1);
}

__global__ __launch_bounds__(1024) void k_scan(const int* __restrict__ counts,
                                               int* __restrict__ ptr) {
  __shared__ int buf[1024];
  __shared__ int s_base;
  const int tid = threadIdx.x;
  if (tid == 0) { s_base = 0; ptr[0] = 0; }
  __syncthreads();
  for (int start = 0; start < Nn; start += 1024) {
    int i = start + tid;
    int v = (i < Nn) ? counts[i] : 0;
    buf[tid] = v;
    __syncthreads();
    for (int off = 1; off < 1024; off <<= 1) {
      int t = (tid >= off) ? buf[tid - off] : 0;
      __syncthreads();
      buf[tid] += t;
      __syncthreads();
    }
    if (i < Nn) ptr[i + 1] = s_base + buf[tid];
    __syncthreads();
    if (tid == 0) s_base += buf[1023];
    __syncthreads();
  }
}

__global__ void k_scatter(const int* __restrict__ rows, const int* __restrict__ cols,
                          const float* __restrict__ w, const int* __restrict__ ptr,
                          int* __restrict__ fill, int* __restrict__ csr_col,
                          float* __restrict__ csr_w) {
  int e = blockIdx.x * 256 + threadIdx.x;
  if (e >= En) return;
  int r = rows[e];
  int pos = atomicAdd(&fill[r], 1);
  int d = ptr[r] + pos;
  csr_col[d] = cols[e];
  csr_w[d] = w[e];
}

// ---------------- SpMM: pb = bf16(0.5 * segment_sum(w * hb[col])) --------------
// r8 known-good: one row per wave; edges strided over 4 lane-groups of 16;
// each lane loads uint4 (8 bf16); x4-deep unroll.
__global__ __launch_bounds__(256) void k_spmm(const int* __restrict__ ptr,
    const int* __restrict__ csr_col, const float* __restrict__ csr_w,
    const unsigned short* __restrict__ hb, unsigned short* __restrict__ pb) {
  const int wave = (blockIdx.x * 256 + threadIdx.x) >> 6;
  const int lane = threadIdx.x & 63;
  const int g = lane >> 4;        // edge group 0..3
  const int fl = lane & 15;       // feature lane: feats fl*8 .. fl*8+7
  if (wave >= Nn) return;
  const int s = ptr[wave], e_end = ptr[wave + 1];
  float acc[8];
#pragma unroll
  for (int j = 0; j < 8; ++j) acc[j] = 0.f;

  auto acc8 = [&](uint4 v, float w) {
    union { unsigned int i; float f; } t;
    t.i = v.x << 16;         acc[0] += w * t.f;
    t.i = v.x & 0xFFFF0000u; acc[1] += w * t.f;
    t.i = v.y << 16;         acc[2] += w * t.f;
    t.i = v.y & 0xFFFF0000u; acc[3] += w * t.f;
    t.i = v.z << 16;         acc[4] += w * t.f;
    t.i = v.z & 0xFFFF0000u; acc[5] += w * t.f;
    t.i = v.w << 16;         acc[6] += w * t.f;
    t.i = v.w & 0xFFFF0000u; acc[7] += w * t.f;
  };

  int e = s + g;
  for (; e + 12 < e_end; e += 16) {
    const int c0 = csr_col[e];
    const int c1 = csr_col[e + 4];
    const int c2 = csr_col[e + 8];
    const int c3 = csr_col[e + 12];
    const float w0 = csr_w[e];
    const float w1 = csr_w[e + 4];
    const float w2 = csr_w[e + 8];
    const float w3 = csr_w[e + 12];
    const uint4 v0 = *(const uint4*)(hb + (size_t)c0 * Hd + fl * 8);
    const uint4 v1 = *(const uint4*)(hb + (size_t)c1 * Hd + fl * 8);
    const uint4 v2 = *(const uint4*)(hb + (size_t)c2 * Hd + fl * 8);
    const uint4 v3 = *(const uint4*)(hb + (size_t)c3 * Hd + fl * 8);
    acc8(v0, w0); acc8(v1, w1); acc8(v2, w2); acc8(v3, w3);
  }
  for (; e + 4 < e_end; e += 8) {
    const int c0 = csr_col[e];
    const int c1 = csr_col[e + 4];
    const float w0 = csr_w[e];
    const float w1 = csr_w[e + 4];
    const uint4 v0 = *(const uint4*)(hb + (size_t)c0 * Hd + fl * 8);
    const uint4 v1 = *(const uint4*)(hb + (size_t)c1 * Hd + fl * 8);
    acc8(v0, w0); acc8(v1, w1);
  }
  if (e < e_end) {
    const int c = csr_col[e];
    const float w = csr_w[e];
    const uint4 v = *(const uint4*)(hb + (size_t)c * Hd + fl * 8);
    acc8(v, w);
  }
#pragma unroll
  for (int j = 0; j < 8; ++j) acc[j] += __shfl_xor(acc[j], 16);
#pragma unroll
  for (int j = 0; j < 8; ++j) acc[j] += __shfl_xor(acc[j], 32);
  if (g == 0) {
    uint4 o;
    o.x = (unsigned int)f2bf(0.5f * acc[0]) | ((unsigned int)f2bf(0.5f * acc[1]) << 16);
    o.y = (unsigned int)f2bf(0.5f * acc[2]) | ((unsigned int)f2bf(0.5f * acc[3]) << 16);
    o.z = (unsigned int)f2bf(0.5f * acc[4]) | ((unsigned int)f2bf(0.5f * acc[5]) << 16);
    o.w = (unsigned int)f2bf(0.5f * acc[6]) | ((unsigned int)f2bf(0.5f * acc[7]) << 16);
    *(uint4*)(pb + (size_t)wave * Hd + fl * 8) = o;
  }
}

// ---------------- layer (MFMA), residual in bf16 hb (in-place) ----------------
__global__ __launch_bounds__(256) void k_layer(const unsigned short* __restrict__ pb,
    const unsigned short* __restrict__ x0b, const unsigned short* __restrict__ Wcp,
    unsigned short* __restrict__ hb, float beta) {
  const int tid = threadIdx.x;
  const int wv = tid >> 6, lane = tid & 63;
  const int lrow = lane & 15, quad = lane >> 4;
  const int row0 = blockIdx.x * 64;
  const int ar = row0 + wv * 16 + lrow;
  f32x4 acc[8];
#pragma unroll
  for (int t = 0; t < 8; ++t) acc[t] = (f32x4){0.f, 0.f, 0.f, 0.f};

#pragma unroll
  for (int kk = 0; kk < 8; ++kk) {
    const unsigned short* src = (kk < 4) ? pb : x0b;
    const int ko = (kk & 3) * 32 + quad * 8;
    const bf16x8 af = *(const bf16x8*)(src + (size_t)ar * Hd + ko);
#pragma unroll
    for (int nt = 0; nt < 8; ++nt) {
      const bf16x8 bf = *(const bf16x8*)(Wcp + ((size_t)(kk * 4 + quad) * 128 + nt * 16 + lrow) * 8);
      acc[nt] = __builtin_amdgcn_mfma_f32_16x16x32_bf16(af, bf, acc[nt], 0, 0, 0);
    }
  }

  __shared__ float sacc[64 * 132];
#pragma unroll
  for (int nt = 0; nt < 8; ++nt)
#pragma unroll
    for (int i = 0; i < 4; ++i)
      sacc[(wv * 16 + quad * 4 + i) * 132 + nt * 16 + lrow] = acc[nt][i];
  __syncthreads();

  const int row = tid >> 2, cs = (tid & 3) * 32;
  const int gr = row0 + row;
  if (gr < Nn) {
    const float om = 1.f - beta;
#pragma unroll
    for (int g = 0; g < 4; ++g) {
      const int c0 = cs + g * 8;
      const u16x8 pv = *(const u16x8*)(pb + (size_t)gr * Hd + c0);
      const u16x8 xv = *(const u16x8*)(x0b + (size_t)gr * Hd + c0);
      const u16x8 hv = *(const u16x8*)(hb + (size_t)gr * Hd + c0);
      float nv[8];
#pragma unroll
      for (int j = 0; j < 8; ++j) {
        const float gemm = sacc[row * 132 + c0 + j];
        const float pj = bf2f(pv[j]);
        const float xj = bf2f(xv[j]);
        const float outv = om * (pj + 0.5f * xj) + beta * gemm;
        nv[j] = fmaxf(bf2f(hv[j]) + outv, 0.f);
      }
      u16x8 ob;
#pragma unroll
      for (int j = 0; j < 8; ++j) ob[j] = f2bf(nv[j]);
      *(u16x8*)(hb + (size_t)gr * Hd + c0) = ob;
    }
  }
}

// ---------------- head (reads bf16 hb) ----------------
__global__ __launch_bounds__(256) void k_head(const unsigned short* __restrict__ hb,
    const float* __restrict__ W2, const float* __restrict__ b2,
    unsigned short* __restrict__ anb, float* __restrict__ p_lc,
    float* __restrict__ out_emb) {
  const int wid = (blockIdx.x * 256 + threadIdx.x) >> 6;
  const int lane = threadIdx.x & 63;
  if (wid >= Bb) return;
  const unsigned short* hr = hb + (size_t)wid * Hd;
  const float v0 = bf2f(hr[lane]), v1 = bf2f(hr[lane + 64]);
  out_emb[wid * Hd + lane] = v0;
  out_emb[wid * Hd + lane + 64] = v1;
  float ss = v0 * v0 + v1 * v1;
#pragma unroll
  for (int off = 32; off > 0; off >>= 1) ss += __shfl_xor(ss, off);
  const float inv = 1.f / fmaxf(sqrtf(ss), 1e-8f);
  anb[wid * Hd + lane] = f2bf(v0 * inv);
  anb[wid * Hd + lane + 64] = f2bf(v1 * inv);
  float l = 0.f;
  if (lane < Cc) {
    for (int k = 0; k < Hd; ++k) l += bf2f(hr[k]) * W2[k * Cc + lane];
    l += b2[lane];
  }
  float lm = (lane < Cc) ? l : -3.0e38f;
#pragma unroll
  for (int off = 32; off > 0; off >>= 1) lm = fmaxf(lm, __shfl_xor(lm, off));
  float ex = (lane < Cc) ? expf(l - lm) : 0.f;
#pragma unroll
  for (int off = 32; off > 0; off >>= 1) ex += __shfl_xor(ex, off);
  const float lse = logf(ex);
  if (lane < Cc) p_lc[wid * Cc + lane] = l - lm - lse;
}

// ---------------- fused sim = an@an^T (bf16 MFMA) with running top-5 ----------
// Round-2 measured-best structure: 256 thr, CH_N=4, guarded everywhere.
// (Guard-free full tiles NaN'd in r5/r6 — do not retry.)
#define CH_N  4
#define CH_SZ 2500
#define SB_LD 136
__global__ __launch_bounds__(256) void k_simtopk(const unsigned short* __restrict__ anb,
    float* __restrict__ cval, int* __restrict__ cidx) {
  __shared__ __align__(16) char smem[40960];
  unsigned short* sb = (unsigned short*)smem;
  const int rt = blockIdx.x / CH_N;
  const int chunk = blockIdx.x % CH_N;
  const int row0 = rt * 64;
  const int cbeg = chunk * CH_SZ;
  const int cend = cbeg + CH_SZ;
  const int tid = threadIdx.x;
  const int wv = tid >> 6;
  const int lane = tid & 63;
  const int lrow = lane & 15;
  const int quad = lane >> 4;

  union Frag { uint4 u4; bf16x8 v; };
  bf16x8 afr[4];
  const int ar = row0 + wv * 16 + lrow;
#pragma unroll
  for (int kq = 0; kq < 4; ++kq) {
    Frag f;
    f.u4 = make_uint4(0u, 0u, 0u, 0u);
    if (ar < Bb) f.u4 = *(const uint4*)(anb + (size_t)ar * Hd + kq * 32 + quad * 8);
    afr[kq] = f.v;
  }

  float bv[4][KT];
  int bi[4][KT];
#pragma unroll
  for (int r = 0; r < 4; ++r)
#pragma unroll
    for (int t = 0; t < KT; ++t) { bv[r][t] = -3.0e38f; bi[r][t] = 0x7fffffff; }

  const int ntile = (CH_SZ + 63) / 64;
  for (int t = 0; t < ntile; ++t) {
    const int c0 = cbeg + t * 64;
    __syncthreads();
    for (int i = tid; i < 1024; i += 256) {
      const int r = i >> 4, ch = i & 15;
      const int gc = c0 + r;
      uint4 v = make_uint4(0u, 0u, 0u, 0u);
      if (gc < cend) v = *(const uint4*)(anb + (size_t)gc * Hd + ch * 8);
      *(uint4*)&sb[r * SB_LD + ch * 8] = v;
    }
    __syncthreads();
#pragma unroll
    for (int sub = 0; sub < 4; ++sub) {
      f32x4 acc = {0.f, 0.f, 0.f, 0.f};
      const int scol = sub * 16 + lrow;
#pragma unroll
      for (int kq = 0; kq < 4; ++kq) {
        bf16x8 bfr = *(const bf16x8*)&sb[scol * SB_LD + kq * 32 + quad * 8];
        acc = __builtin_amdgcn_mfma_f32_16x16x32_bf16(afr[kq], bfr, acc, 0, 0, 0);
      }
      const int gc = c0 + scol;
      const bool ok = gc < cend;
#pragma unroll
      for (int i = 0; i < 4; ++i) {
        const float v = ok ? acc[i] : -3.0e38f;
        if (v > bv[i][KT - 1]) {
          float tv = v; int ti = gc;
#pragma unroll
          for (int s = 0; s < KT; ++s) {
            if (tv > bv[i][s]) {
              float ov = bv[i][s]; int oi = bi[i][s];
              bv[i][s] = tv; bi[i][s] = ti; tv = ov; ti = oi;
            }
          }
        }
      }
    }
  }

  __syncthreads();
  float* mv = (float*)smem;
  int* mi = (int*)(smem + 20480);
#pragma unroll
  for (int i = 0; i < 4; ++i) {
    const int row = wv * 16 + quad * 4 + i;
#pragma unroll
    for (int t = 0; t < KT; ++t) {
      mv[row * 80 + lrow * KT + t] = bv[i][t];
      mi[row * 80 + lrow * KT + t] = bi[i][t];
    }
  }
  __syncthreads();
  if (tid < 64) {
    const int gr = row0 + tid;
    if (gr < Bb) {
      float tv5[KT]; int ti5[KT];
#pragma unroll
      for (int t = 0; t < KT; ++t) { tv5[t] = -3.0e38f; ti5[t] = 0x7fffffff; }
      for (int m = 0; m < 80; ++m) {
        float v = mv[tid * 80 + m]; int id = mi[tid * 80 + m];
        if (v > tv5[KT - 1] || (v == tv5[KT - 1] && id < ti5[KT - 1])) {
#pragma unroll
          for (int s = 0; s < KT; ++s) {
            if (v > tv5[s] || (v == tv5[s] && id < ti5[s])) {
              float ov = tv5[s]; int oi = ti5[s];
              tv5[s] = v; ti5[s] = id; v = ov; id = oi;
            }
          }
        }
      }
#pragma unroll
      for (int t = 0; t < KT; ++t) {
        cval[gr * (CH_N * KT) + chunk * KT + t] = tv5[t];
        cidx[gr * (CH_N * KT) + chunk * KT + t] = ti5[t];
      }
    }
  }
}

// ---------------- final ----------------
__global__ __launch_bounds__(256) void k_final(const float* __restrict__ cval,
    const int* __restrict__ cidx, const int* __restrict__ y,
    const float* __restrict__ p_lc, float* __restrict__ out_final) {
  const int b = blockIdx.x * 256 + threadIdx.x;
  if (b >= Bb) return;
  float tv5[KT]; int ti5[KT];
#pragma unroll
  for (int t = 0; t < KT; ++t) { tv5[t] = -3.0e38f; ti5[t] = 0x7fffffff; }
#pragma unroll
  for (int m = 0; m < CH_N * KT; ++m) {
    float v = cval[b * (CH_N * KT) + m]; int id = cidx[b * (CH_N * KT) + m];
    if (v > tv5[KT - 1] || (v == tv5[KT - 1] && id < ti5[KT - 1])) {
#pragma unroll
      for (int t = 0; t < KT; ++t) {
        if (v > tv5[t] || (v == tv5[t] && id < ti5[t])) {
          float ov = tv5[t]; int oi = ti5[t];
          tv5[t] = v; ti5[t] = id; v = ov; id = oi;
        }
      }
    }
  }
  float w[KT]; int cls[KT];
#pragma unroll
  for (int t = 0; t < KT; ++t) { w[t] = expf(tv5[t]); cls[t] = y[ti5[t]]; }
  float m = -3.0e38f;
  for (int c = 0; c < Cc; ++c) {
    float f = 0.f;
#pragma unroll
    for (int t = 0; t < KT; ++t) f += (cls[t] == c) ? w[t] : 0.f;
    m = fmaxf(m, f);
  }
  float s = 0.f;
  for (int c = 0; c < Cc; ++c) {
    float f = 0.f;
#pragma unroll
    for (int t = 0; t < KT; ++t) f += (cls[t] == c) ? w[t] : 0.f;
    s += expf(f - m);
  }
  const float lse = logf(s);
  for (int c = 0; c < Cc; ++c) {
    float f = 0.f;
#pragma unroll
    for (int t = 0; t < KT; ++t) f += (cls[t] == c) ? w[t] : 0.f;
    out_final[b * Cc + c] = 0.5f * p_lc[b * Cc + c] + 0.5f * (f - m - lse);
  }
}

extern "C" void kernel_launch(void* const* d_in, const int* in_sizes, int n_in,
                              void* d_out, int out_size, void* d_ws, size_t ws_size,
                              hipStream_t stream) {
  const float* x  = (const float*)d_in[0];
  const int* erow = (const int*)d_in[1];
  const int* ecol = erow + En;
  const float* ew = (const float*)d_in[2];
  const int* y    = (const int*)d_in[3];
  const float* W1 = (const float*)d_in[5];
  const float* b1 = (const float*)d_in[6];
  const float* cw1 = (const float*)d_in[7];
  const float* cw2 = (const float*)d_in[8];
  const float* W2 = (const float*)d_in[9];
  const float* b2 = (const float*)d_in[10];
  float* out = (float*)d_out;

  float* ws = (float*)d_ws;
  size_t off = 0;
  float* plc = ws + off; off += (size_t)Bb * Cc;
  float* cval = ws + off; off += (size_t)Bb * (CH_N * KT);
  int* cidx  = (int*)(ws + off); off += (size_t)Bb * (CH_N * KT);
  int* counts = (int*)(ws + off); off += Nn;
  int* fill   = (int*)(ws + off); off += Nn;
  int* rptr   = (int*)(ws + off); off += Nn + 4;
  int* ccol   = (int*)(ws + off); off += En;
  float* cwt  = ws + off; off += En;
  unsigned short* anb = (unsigned short*)(ws + off); off += (size_t)Bb * Hd / 2;
  unsigned short* hb  = (unsigned short*)(ws + off); off += (size_t)NR * Hd / 2;
  unsigned short* x0b = (unsigned short*)(ws + off); off += (size_t)NR * Hd / 2;
  unsigned short* pb  = (unsigned short*)(ws + off); off += (size_t)NR * Hd / 2;
  unsigned short* W1p = (unsigned short*)(ws + off); off += 65536 / 2;
  unsigned short* Wcp = (unsigned short*)(ws + off); off += 294912 / 2;

  k_pack_w1<<<256, 256, 0, stream>>>(W1, W1p);
  k_pack_wc<<<1152, 256, 0, stream>>>(cw1, cw2, Wcp);
  k_in<<<NR / 64, 256, 0, stream>>>(x, W1p, b1, hb, x0b);
  hipMemsetAsync(counts, 0, (size_t)2 * Nn * sizeof(int), stream);
  k_hist<<<(En + 255) / 256, 256, 0, stream>>>(erow, counts);
  k_scan<<<1, 1024, 0, stream>>>(counts, rptr);
  k_scatter<<<(En + 255) / 256, 256, 0, stream>>>(erow, ecol, ew, rptr, fill, ccol, cwt);
  for (int l = 0; l < Ll; ++l) {
    const float beta = logf(1.0f / (float)(l + 1) + 1.0f);
    k_spmm<<<(Nn * 64 + 255) / 256, 256, 0, stream>>>(rptr, ccol, cwt, hb, pb);
    k_layer<<<NR / 64, 256, 0, stream>>>(pb, x0b, Wcp + (size_t)l * 32768, hb, beta);
  }
  k_head<<<(Bb * 64) / 256, 256, 0, stream>>>(hb, W2, b2, anb, plc, out + (size_t)Bb * Cc);
  k_simtopk<<<((Bb + 63) / 64) * CH_N, 256, 0, stream>>>(anb, cval, cidx);
  k_final<<<(Bb + 255) / 256, 256, 0, stream>>>(cval, cidx, y, plc, out);
}